// Round 10
// baseline (424.505 us; speedup 1.0000x reference)
//
#include <hip/hip_runtime.h>

// KAN forward: 3 layers of [deg-3 B-spline basis (64 bases) -> einsum 'bik,ijk->bj'].
// Only 4 basis values are nonzero per point => 4-tap gather per (i,j).
//
// NUMERICS (frozen since R6 — absmax sits exactly at threshold; per-(b,j)
// product set and fp64 add order must stay bitwise-identical):
//  * knots: jnp.linspace fp32 semantics, endpoint forced to 1.0f
//  * basis: fp32 Cox-de Boor, reference expression tree, contraction OFF
//  * einsum: fp64 accumulation, per-(b,j) order = i ascending, k ascending
//    (shift-aligned w' slots: +/-0-product adds are bitwise no-ops, validated
//    R7-R9; fused epilogue feeds the SAME fp32 activation value to basis4)
//
// PERF history: R6 1967us -> R7 711 (LDS-staged) -> R8 636 (32j tiles) ->
// R9 420 (no LDS/barriers; layer2 195us, latency-bound at 40% VALU, grid-capped
// occupancy).  R10: precomp FUSED into gather epilogue (kills 2 dispatches +
// activation round-trip), C(i+1) register prefetch (tables at distance 2),
// JPT=2 -> grid 2048, __launch_bounds__(256,8) for a 32-wave/CU cap.

#define NBATCH 4096

typedef float f4a __attribute__((ext_vector_type(4), aligned(4)));

// jnp.linspace(0,1,68,f32): delta = fl32(1/67); K[m] = fl32(m)*delta; K[67]=1.
__device__ __forceinline__ float knotf(int m) {
    if (m == 67) return 1.0f;
    return (float)m * (1.0f / 67.0f);
}

// Bitwise replica of the reference Cox-de Boor recursion on the 7-wide
// nonzero window around span t.  w[r] = B_{t-3+r,3}(x), r=0..3.
__device__ __forceinline__ void basis4(float xf, int& t_out, float w[4]) {
#pragma clang fp contract(off)
    int t = (int)floorf(xf * 67.0f);
    t = t < 0 ? 0 : (t > 66 ? 66 : t);
    #pragma unroll
    for (int it = 0; it < 2; ++it) {   // enforce K[t] <= x < K[t+1] on fp32 knots
        if (t > 0 && xf < knotf(t)) --t;
        else if (t < 66 && xf >= knotf(t + 1)) ++t;
    }
    float W[7];
    #pragma unroll
    for (int j = 0; j < 7; ++j) W[j] = 0.0f;
    W[3] = 1.0f;   // degree-0 indicator at span t
    #pragma unroll
    for (int d = 1; d <= 3; ++d) {
        #pragma unroll
        for (int j = 0; j <= 6 - d; ++j) {
            const int k = t - 3 + j;
            const float ka = knotf(k);
            const float kb = knotf(k + d);
            const float kc = knotf(k + d + 1);
            const float ke = knotf(k + 1);
            const float lt = ((xf - ka) / (kb - ka)) * W[j];
            const float rt = ((kc - xf) / (kc - ke)) * W[j + 1];
            W[j] = lt + rt;
        }
    }
    t_out = t;
    w[0] = W[0]; w[1] = W[1]; w[2] = W[2]; w[3] = W[3];
}

// Shift-aligned table entry: k0 = clamp(t-3,0,60); w'[m] applies to C[k0+m],
// m-ascending == k-ascending == R6 order; displaced/OOB slots get w'=0.
__device__ __forceinline__ void make_wk(float xf, float4& wv, int& kv) {
    float wp[4] = {0.f, 0.f, 0.f, 0.f};
    int k0 = 0;
    if (xf >= 0.0f && xf < 1.0f) {
        int t; float w[4];
        basis4(xf, t, w);
        k0 = t - 3;
        k0 = k0 < 0 ? 0 : (k0 > 60 ? 60 : k0);
        const int s = (t - 3) - k0;
        #pragma unroll
        for (int m = 0; m < 4; ++m) {
            const int r = m - s;
            wp[m] = (r >= 0 && r <= 3) ? w[r] : 0.0f;
        }
    }
    wv = make_float4(wp[0], wp[1], wp[2], wp[3]);
    kv = k0;
}

// ---------------- precompute from x (layer-1 tables only) -------------------
__global__ __launch_bounds__(256) void precomp_x(const float* __restrict__ x,
        float4* __restrict__ wtab, int* __restrict__ ktab) {
    const int gid = blockIdx.x * 256 + threadIdx.x;   // gid = i*4096 + b, i<64
    const int i = gid >> 12;
    const int b = gid & 4095;
    float4 wv; int kv;
    make_wk(x[(size_t)b * 64 + i], wv, kv);
    wtab[gid] = wv;
    ktab[gid] = kv;
}

// ---------------- direct gather, fused next-layer precomp -------------------
// Block = 64 b-lanes x 4 j-threads; thread owns JPT consecutive j.  Wave spans
// 64 b for one j-group => C float4 wave-loads land in one 256B row (L1-hot).
// Pipeline: tables prefetched at distance 2, C rows at distance 1.
// Epilogue: FUSE -> compute next layer's (w,k0) from the in-register fp32
// activation and store (coalesced per m); else write final out[b][j].
template<int IN, int OUT, int JPT, bool FUSE>
__global__ __launch_bounds__(256, 8) void kan_direct_f(
        const float* __restrict__ Cg, const float4* __restrict__ wtab,
        const int* __restrict__ ktab, float4* __restrict__ wnext,
        int* __restrict__ knext, float* __restrict__ outp) {
    constexpr int JSPAN = 4 * JPT;
    constexpr int NJT = OUT / JSPAN;
    const int bid = blockIdx.x, tid = threadIdx.x;
    const int jt   = bid % NJT;       // XCD-swizzle: consecutive bids spread XCDs
    const int bblk = bid / NJT;
    const int bl = tid & 63;
    const int jc = tid >> 6;
    const int j0 = jt * JSPAN + jc * JPT;
    const int b  = bblk * 64 + bl;

    double acc[JPT];
    #pragma unroll
    for (int m = 0; m < JPT; ++m) acc[m] = 0.0;

    // pipeline preamble
    float4 wA = wtab[b];
    int    kA = ktab[b];
    float4 wB = wA;
    int    kB = kA;
    if (IN > 1) { wB = wtab[4096 + b]; kB = ktab[4096 + b]; }

    f4a cc[JPT];
    {
        const float* base = Cg + (size_t)j0 * 64 + kA;
        #pragma unroll
        for (int m = 0; m < JPT; ++m) cc[m] = *(const f4a*)(base + m * 64);
    }

    for (int i = 0; i < IN; ++i) {
        const int ip1 = (i + 1 < IN) ? i + 1 : IN - 1;
        const int ip2 = (i + 2 < IN) ? i + 2 : IN - 1;
        // prefetch C(i+1) using kB
        f4a cn[JPT];
        const float* baseN = Cg + ((size_t)ip1 * OUT + j0) * 64 + kB;
        #pragma unroll
        for (int m = 0; m < JPT; ++m) cn[m] = *(const f4a*)(baseN + m * 64);
        // prefetch tables (i+2)
        const float4 wC = wtab[(size_t)ip2 * 4096 + b];
        const int    kC = ktab[(size_t)ip2 * 4096 + b];
        // compute on current (k ascending == R6 order)
        const double w0 = (double)wA.x, w1 = (double)wA.y;
        const double w2 = (double)wA.z, w3 = (double)wA.w;
        #pragma unroll
        for (int m = 0; m < JPT; ++m) {
            acc[m] = fma(w0, (double)cc[m].x, acc[m]);
            acc[m] = fma(w1, (double)cc[m].y, acc[m]);
            acc[m] = fma(w2, (double)cc[m].z, acc[m]);
            acc[m] = fma(w3, (double)cc[m].w, acc[m]);
        }
        // rotate
        wA = wB; kA = kB; wB = wC; kB = kC;
        #pragma unroll
        for (int m = 0; m < JPT; ++m) cc[m] = cn[m];
    }

    if (FUSE) {
        #pragma unroll
        for (int m = 0; m < JPT; ++m) {
            const float af = (float)acc[m];   // same fp32 activation as R9 stored
            float4 wv; int kv;
            make_wk(af, wv, kv);
            const size_t idx = (size_t)(j0 + m) * 4096 + b;
            wnext[idx] = wv;
            knext[idx] = kv;
        }
    } else {
        #pragma unroll
        for (int m = 0; m < JPT; ++m)
            outp[(size_t)b * OUT + j0 + m] = (float)acc[m];
    }
}

// ---------------- tier B: R9 proven path (29.4 MB workspace) ----------------

__global__ __launch_bounds__(256) void precomp_basis(const float* __restrict__ act,
        int IN, int transposed, float4* __restrict__ wtab, int* __restrict__ ktab,
        int total) {
    int gid = blockIdx.x * 256 + threadIdx.x;
    if (gid >= total) return;
    const int i = gid >> 12;
    const int b = gid & 4095;
    const float xf = transposed ? act[gid] : act[(size_t)b * IN + i];
    float4 wv; int kv;
    make_wk(xf, wv, kv);
    wtab[gid] = wv;
    ktab[gid] = kv;
}

template<int IN, int OUT, int JPT, bool TSTORE>
__global__ __launch_bounds__(256) void kan_direct(const float* __restrict__ Cg,
        const float4* __restrict__ wtab, const int* __restrict__ ktab,
        float* __restrict__ aout) {
    constexpr int JSPAN = 4 * JPT;
    constexpr int NJT = OUT / JSPAN;
    const int bid = blockIdx.x, tid = threadIdx.x;
    const int jt   = bid % NJT;
    const int bblk = bid / NJT;
    const int bl = tid & 63;
    const int jc = tid >> 6;
    const int j0 = jt * JSPAN + jc * JPT;
    const int b  = bblk * 64 + bl;

    double acc[JPT];
    #pragma unroll
    for (int m = 0; m < JPT; ++m) acc[m] = 0.0;

    float4 wv = wtab[b];
    int    kv = ktab[b];
    const float* Crow = Cg + (size_t)j0 * 64;

    for (int i = 0; i < IN; ++i) {
        const float4 wcur = wv;
        const int    kcur = kv;
        if (i + 1 < IN) {
            wv = wtab[(size_t)(i + 1) * 4096 + b];
            kv = ktab[(size_t)(i + 1) * 4096 + b];
        }
        const float* base = Crow + kcur;
        const double w0 = (double)wcur.x, w1 = (double)wcur.y;
        const double w2 = (double)wcur.z, w3 = (double)wcur.w;
        #pragma unroll
        for (int m = 0; m < JPT; ++m) {
            const f4a c = *(const f4a*)(base + m * 64);
            acc[m] = fma(w0, (double)c.x, acc[m]);
            acc[m] = fma(w1, (double)c.y, acc[m]);
            acc[m] = fma(w2, (double)c.z, acc[m]);
            acc[m] = fma(w3, (double)c.w, acc[m]);
        }
        Crow += (size_t)OUT * 64;
    }

    if (TSTORE) {
        #pragma unroll
        for (int m = 0; m < JPT; ++m)
            aout[(size_t)(j0 + m) * 4096 + b] = (float)acc[m];
    } else {
        #pragma unroll
        for (int m = 0; m < JPT; ++m)
            aout[(size_t)b * OUT + j0 + m] = (float)acc[m];
    }
}

// ---------------- tier C: R6 monolithic (zero workspace, proven) ------------

__device__ __forceinline__ void stage1(float xf, float sw[4], int& st) {
    const bool inr = (xf >= 0.0f) && (xf < 1.0f);
    if (!inr) { st = -1; sw[0] = sw[1] = sw[2] = sw[3] = 0.0f; return; }
    int t; float w[4];
    basis4(xf, t, w);
    sw[0] = w[0]; sw[1] = w[1]; sw[2] = w[2]; sw[3] = w[3];
    st = t;
}

template<int IN, int OUT>
__device__ __forceinline__ float gather_acc(const float* __restrict__ C, int j,
                                            const float (*__restrict__ sw)[4],
                                            const int* __restrict__ st) {
    double acc = 0.0;
    for (int i = 0; i < IN; ++i) {
        const int t = st[i];
        if (t < 0) continue;
        const float* Crow = C + ((size_t)i * OUT + j) * 64;
        #pragma unroll
        for (int r = 0; r < 4; ++r) {
            const int k4 = t - 3 + r;
            if (k4 >= 0 && k4 <= 63)
                acc += (double)sw[i][r] * (double)Crow[k4];
        }
    }
    return (float)acc;
}

__global__ __launch_bounds__(256) void kan_fused(const float* __restrict__ x,
                                                 const float* __restrict__ C0,
                                                 const float* __restrict__ C1,
                                                 const float* __restrict__ C2,
                                                 float* __restrict__ out) {
    __shared__ float cur[256];
    __shared__ float sw[256][4];
    __shared__ int   st[256];
    const int b = blockIdx.x, tid = threadIdx.x;

    if (tid < 64) stage1(x[(size_t)b * 64 + tid], sw[tid], st[tid]);
    __syncthreads();
    {
        const float a = gather_acc<64, 256>(C0, tid, sw, st);
        __syncthreads();
        cur[tid] = a;
    }
    __syncthreads();

    stage1(cur[tid], sw[tid], st[tid]);
    __syncthreads();
    {
        const float a = gather_acc<256, 256>(C1, tid, sw, st);
        __syncthreads();
        cur[tid] = a;
    }
    __syncthreads();

    stage1(cur[tid], sw[tid], st[tid]);
    __syncthreads();
    if (tid < 64) out[(size_t)b * 64 + tid] = gather_acc<256, 64>(C2, tid, sw, st);
}

// ---------------- launcher --------------------------------------------------

extern "C" void kernel_launch(void* const* d_in, const int* in_sizes, int n_in,
                              void* d_out, int out_size, void* d_ws, size_t ws_size,
                              hipStream_t stream) {
    const float* x  = (const float*)d_in[0];   // (4096, 64)
    const float* C0 = (const float*)d_in[1];   // (64, 256, 64)
    const float* C1 = (const float*)d_in[2];   // (256, 256, 64)
    const float* C2 = (const float*)d_in[3];   // (256, 64, 64)
    float* out = (float*)d_out;                // (4096, 64)

    const size_t WTAB = (size_t)4096 * 256 * 16;   // 16.78 MB (float4 per (i,b))
    const size_t KTAB = (size_t)4096 * 256 * 4;    //  4.19 MB
    const size_t ACT  = (size_t)4096 * 256 * 4;    //  4.19 MB
    const size_t needA = 2 * (WTAB + KTAB);        // 41.94 MB (ping-pong tables)
    const size_t needB = WTAB + KTAB + 2 * ACT;    // 29.36 MB (R9 proven)

    if (ws_size >= needA) {
        float4* wA = (float4*)d_ws;
        int*    kA = (int*)((char*)d_ws + WTAB);
        float4* wB = (float4*)((char*)d_ws + WTAB + KTAB);
        int*    kB = (int*)((char*)d_ws + 2 * WTAB + KTAB);

        precomp_x<<<1024, 256, 0, stream>>>(x, wA, kA);
        kan_direct_f<64,  256, 2, true ><<<2048, 256, 0, stream>>>(C0, wA, kA, wB, kB, nullptr);
        kan_direct_f<256, 256, 2, true ><<<2048, 256, 0, stream>>>(C1, wB, kB, wA, kA, nullptr);
        kan_direct_f<256, 64,  1, false><<<1024, 256, 0, stream>>>(C2, wA, kA, nullptr, nullptr, out);
    } else if (ws_size >= needB) {
        float4* wtab = (float4*)d_ws;
        int*    ktab = (int*)((char*)d_ws + WTAB);
        float*  a1T  = (float*)((char*)d_ws + WTAB + KTAB);
        float*  a2T  = a1T + (size_t)4096 * 256;

        precomp_basis<<<1024, 256, 0, stream>>>(x, 64, 0, wtab, ktab, 64 * 4096);
        kan_direct<64, 256, 4, true><<<1024, 256, 0, stream>>>(C0, wtab, ktab, a1T);
        precomp_basis<<<4096, 256, 0, stream>>>(a1T, 256, 1, wtab, ktab, 256 * 4096);
        kan_direct<256, 256, 4, true><<<1024, 256, 0, stream>>>(C1, wtab, ktab, a2T);
        precomp_basis<<<4096, 256, 0, stream>>>(a2T, 256, 1, wtab, ktab, 256 * 4096);
        kan_direct<256, 64, 1, false><<<1024, 256, 0, stream>>>(C2, wtab, ktab, out);
    } else {
        kan_fused<<<NBATCH, 256, 0, stream>>>(x, C0, C1, C2, out);
    }
}

// Round 11
// 403.824 us; speedup vs baseline: 1.0512x; 1.0512x over previous
//
#include <hip/hip_runtime.h>

// KAN forward: 3 layers of [deg-3 B-spline basis (64 bases) -> einsum 'bik,ijk->bj'].
// Only 4 basis values are nonzero per point => 4-tap gather per (i,j).
//
// NUMERICS (frozen since R6 — absmax sits exactly at threshold; per-(b,j)
// product set and fp64 add order must stay bitwise-identical):
//  * knots: jnp.linspace fp32 semantics, endpoint forced to 1.0f
//  * basis: fp32 Cox-de Boor, reference expression tree, contraction OFF
//  * einsum: fp64 accumulation, per-(b,j) order = i ascending, k ascending
//    (shift-aligned w' slots: +/-0-product adds are bitwise no-ops, R7-R10)
//
// PERF history: R6 1967 -> R7 711 (LDS) -> R8 636 -> R9 420 (no-LDS row path,
// layer2 195us) -> R10 424 NEUTRAL (JPT2 overhead == fusion gain; occupancy
// was not the limiter).  R11: COLUMN-PARALLEL gather — wave = one b, lanes
// span j; k0/w are wave-uniform => SGPR row addressing (readfirstlane),
// broadcast table loads (/64 table traffic), scalar weights into v_fma_f64.
// Needs C transposed to Ct[i][k][j]; workspace choreographed into the exact
// 41.94 MB proven in R10 (a1 parks in Ct1 buffer pre-transpose).

#define NBATCH 4096

typedef float f4a __attribute__((ext_vector_type(4), aligned(4)));

// jnp.linspace(0,1,68,f32): delta = fl32(1/67); K[m] = fl32(m)*delta; K[67]=1.
__device__ __forceinline__ float knotf(int m) {
    if (m == 67) return 1.0f;
    return (float)m * (1.0f / 67.0f);
}

// Bitwise replica of the reference Cox-de Boor recursion on the 7-wide
// nonzero window around span t.  w[r] = B_{t-3+r,3}(x), r=0..3.
__device__ __forceinline__ void basis4(float xf, int& t_out, float w[4]) {
#pragma clang fp contract(off)
    int t = (int)floorf(xf * 67.0f);
    t = t < 0 ? 0 : (t > 66 ? 66 : t);
    #pragma unroll
    for (int it = 0; it < 2; ++it) {   // enforce K[t] <= x < K[t+1] on fp32 knots
        if (t > 0 && xf < knotf(t)) --t;
        else if (t < 66 && xf >= knotf(t + 1)) ++t;
    }
    float W[7];
    #pragma unroll
    for (int j = 0; j < 7; ++j) W[j] = 0.0f;
    W[3] = 1.0f;   // degree-0 indicator at span t
    #pragma unroll
    for (int d = 1; d <= 3; ++d) {
        #pragma unroll
        for (int j = 0; j <= 6 - d; ++j) {
            const int k = t - 3 + j;
            const float ka = knotf(k);
            const float kb = knotf(k + d);
            const float kc = knotf(k + d + 1);
            const float ke = knotf(k + 1);
            const float lt = ((xf - ka) / (kb - ka)) * W[j];
            const float rt = ((kc - xf) / (kc - ke)) * W[j + 1];
            W[j] = lt + rt;
        }
    }
    t_out = t;
    w[0] = W[0]; w[1] = W[1]; w[2] = W[2]; w[3] = W[3];
}

// Shift-aligned table entry: k0 = clamp(t-3,0,60); w'[m] applies to C[k0+m],
// m-ascending == k-ascending == R6 order; displaced/OOB slots get w'=0.
__device__ __forceinline__ void make_wk(float xf, float4& wv, int& kv) {
    float wp[4] = {0.f, 0.f, 0.f, 0.f};
    int k0 = 0;
    if (xf >= 0.0f && xf < 1.0f) {
        int t; float w[4];
        basis4(xf, t, w);
        k0 = t - 3;
        k0 = k0 < 0 ? 0 : (k0 > 60 ? 60 : k0);
        const int s = (t - 3) - k0;
        #pragma unroll
        for (int m = 0; m < 4; ++m) {
            const int r = m - s;
            wp[m] = (r >= 0 && r <= 3) ? w[r] : 0.0f;
        }
    }
    wv = make_float4(wp[0], wp[1], wp[2], wp[3]);
    kv = k0;
}

// ---------------- table precompute ------------------------------------------
__global__ __launch_bounds__(256) void precomp_x(const float* __restrict__ x,
        float4* __restrict__ wtab, int* __restrict__ ktab) {
    const int gid = blockIdx.x * 256 + threadIdx.x;   // gid = i*4096 + b, i<64
    const int i = gid >> 12;
    const int b = gid & 4095;
    float4 wv; int kv;
    make_wk(x[(size_t)b * 64 + i], wv, kv);
    wtab[gid] = wv;
    ktab[gid] = kv;
}

__global__ __launch_bounds__(256) void precomp_basis(const float* __restrict__ act,
        int IN, int transposed, float4* __restrict__ wtab, int* __restrict__ ktab,
        int total) {
    int gid = blockIdx.x * 256 + threadIdx.x;
    if (gid >= total) return;
    const int i = gid >> 12;
    const int b = gid & 4095;
    const float xf = transposed ? act[gid] : act[(size_t)b * IN + i];
    float4 wv; int kv;
    make_wk(xf, wv, kv);
    wtab[gid] = wv;
    ktab[gid] = kv;
}

// ---------------- C transpose: C[i][j][k] -> Ct[i][k][j] --------------------
template<int OUT>
__global__ void transpose_nt(const float* __restrict__ C, float* __restrict__ Ct) {
    __shared__ float tile[32][33];
    const int i  = blockIdx.z;
    const int k0 = blockIdx.x * 32;   // 64/32 = 2 k-tiles
    const int j0 = blockIdx.y * 32;
    const float* src = C + (size_t)i * OUT * 64;
    #pragma unroll
    for (int r = threadIdx.y; r < 32; r += 8)
        tile[r][threadIdx.x] = src[(size_t)(j0 + r) * 64 + (k0 + threadIdx.x)];
    __syncthreads();
    float* dst = Ct + (size_t)i * 64 * OUT;
    #pragma unroll
    for (int r = threadIdx.y; r < 32; r += 8)
        dst[(size_t)(k0 + r) * OUT + (j0 + threadIdx.x)] = tile[threadIdx.x][r];
}

// ---------------- column-parallel gather (OUT=256 layers) -------------------
// Wave = one b; lane owns j-quad [4*lane .. 4*lane+3].  k0/w wave-uniform:
// k0 forced to SGPR via readfirstlane => scalar row addressing; table loads
// are single broadcast reads; 4 coalesced 1KB row-loads per (b,i).
// fp64 chain per (b,j): i ascending, k ascending — bitwise == R6.
template<int IN>
__global__ __launch_bounds__(256, 8) void kan_colgather(
        const float* __restrict__ Ct,          // [IN][64][256]
        const float4* __restrict__ wtab, const int* __restrict__ ktab,
        float* __restrict__ aout) {            // [4096][256]
    const int tid  = threadIdx.x;
    const int lane = tid & 63;
    const int b    = blockIdx.x * 4 + (tid >> 6);
    const int j0   = lane * 4;

    double acc[4] = {0.0, 0.0, 0.0, 0.0};

    // table pipeline (distance 2); k held as wave-uniform scalar
    float4 wA = wtab[b];
    int    kA = __builtin_amdgcn_readfirstlane(ktab[b]);
    float4 wB = wA; int kB = kA;
    if (IN > 1) {
        wB = wtab[4096 + b];
        kB = __builtin_amdgcn_readfirstlane(ktab[4096 + b]);
    }

    // C row pipeline (distance 1): 4 tap rows in flight
    f4a c0, c1, c2, c3;
    {
        const float* base = Ct + (size_t)kA * 256 + j0;
        c0 = *(const f4a*)(base);
        c1 = *(const f4a*)(base + 256);
        c2 = *(const f4a*)(base + 512);
        c3 = *(const f4a*)(base + 768);
    }

    for (int i = 0; i < IN; ++i) {
        const int ip1 = (i + 1 < IN) ? i + 1 : IN - 1;
        const int ip2 = (i + 2 < IN) ? i + 2 : IN - 1;
        // prefetch C(i+1) rows via kB
        f4a n0, n1, n2, n3;
        {
            const float* bn = Ct + ((size_t)ip1 * 64 + kB) * 256 + j0;
            n0 = *(const f4a*)(bn);
            n1 = *(const f4a*)(bn + 256);
            n2 = *(const f4a*)(bn + 512);
            n3 = *(const f4a*)(bn + 768);
        }
        // prefetch tables (i+2)
        const float4 wC = wtab[(size_t)ip2 * 4096 + b];
        const int    kC = __builtin_amdgcn_readfirstlane(ktab[(size_t)ip2 * 4096 + b]);
        // compute current i: k ascending per j — R6 order
        const double w0 = (double)wA.x, w1 = (double)wA.y;
        const double w2 = (double)wA.z, w3 = (double)wA.w;
        #pragma unroll
        for (int e = 0; e < 4; ++e) {
            acc[e] = fma(w0, (double)c0[e], acc[e]);
            acc[e] = fma(w1, (double)c1[e], acc[e]);
            acc[e] = fma(w2, (double)c2[e], acc[e]);
            acc[e] = fma(w3, (double)c3[e], acc[e]);
        }
        wA = wB; kA = kB; wB = wC; kB = kC;
        c0 = n0; c1 = n1; c2 = n2; c3 = n3;
    }

    const float4 o = make_float4((float)acc[0], (float)acc[1],
                                 (float)acc[2], (float)acc[3]);
    *(float4*)(aout + (size_t)b * 256 + j0) = o;   // coalesced 1KB/wave
}

// ---------------- row-parallel gather (layer 3 + tier B, proven R9) ---------
template<int IN, int OUT, int JPT, bool TSTORE>
__global__ __launch_bounds__(256) void kan_direct(const float* __restrict__ Cg,
        const float4* __restrict__ wtab, const int* __restrict__ ktab,
        float* __restrict__ aout) {
    constexpr int JSPAN = 4 * JPT;
    constexpr int NJT = OUT / JSPAN;
    const int bid = blockIdx.x, tid = threadIdx.x;
    const int jt   = bid % NJT;
    const int bblk = bid / NJT;
    const int bl = tid & 63;
    const int jc = tid >> 6;
    const int j0 = jt * JSPAN + jc * JPT;
    const int b  = bblk * 64 + bl;

    double acc[JPT];
    #pragma unroll
    for (int m = 0; m < JPT; ++m) acc[m] = 0.0;

    float4 wv = wtab[b];
    int    kv = ktab[b];
    const float* Crow = Cg + (size_t)j0 * 64;

    for (int i = 0; i < IN; ++i) {
        const float4 wcur = wv;
        const int    kcur = kv;
        if (i + 1 < IN) {
            wv = wtab[(size_t)(i + 1) * 4096 + b];
            kv = ktab[(size_t)(i + 1) * 4096 + b];
        }
        const float* base = Crow + kcur;
        const double w0 = (double)wcur.x, w1 = (double)wcur.y;
        const double w2 = (double)wcur.z, w3 = (double)wcur.w;
        #pragma unroll
        for (int m = 0; m < JPT; ++m) {
            const f4a c = *(const f4a*)(base + m * 64);
            acc[m] = fma(w0, (double)c.x, acc[m]);
            acc[m] = fma(w1, (double)c.y, acc[m]);
            acc[m] = fma(w2, (double)c.z, acc[m]);
            acc[m] = fma(w3, (double)c.w, acc[m]);
        }
        Crow += (size_t)OUT * 64;
    }

    if (TSTORE) {
        #pragma unroll
        for (int m = 0; m < JPT; ++m)
            aout[(size_t)(j0 + m) * 4096 + b] = (float)acc[m];
    } else {
        #pragma unroll
        for (int m = 0; m < JPT; ++m)
            aout[(size_t)b * OUT + j0 + m] = (float)acc[m];
    }
}

// ---------------- tier C: R6 monolithic (zero workspace, proven) ------------

__device__ __forceinline__ void stage1(float xf, float sw[4], int& st) {
    const bool inr = (xf >= 0.0f) && (xf < 1.0f);
    if (!inr) { st = -1; sw[0] = sw[1] = sw[2] = sw[3] = 0.0f; return; }
    int t; float w[4];
    basis4(xf, t, w);
    sw[0] = w[0]; sw[1] = w[1]; sw[2] = w[2]; sw[3] = w[3];
    st = t;
}

template<int IN, int OUT>
__device__ __forceinline__ float gather_acc(const float* __restrict__ C, int j,
                                            const float (*__restrict__ sw)[4],
                                            const int* __restrict__ st) {
    double acc = 0.0;
    for (int i = 0; i < IN; ++i) {
        const int t = st[i];
        if (t < 0) continue;
        const float* Crow = C + ((size_t)i * OUT + j) * 64;
        #pragma unroll
        for (int r = 0; r < 4; ++r) {
            const int k4 = t - 3 + r;
            if (k4 >= 0 && k4 <= 63)
                acc += (double)sw[i][r] * (double)Crow[k4];
        }
    }
    return (float)acc;
}

__global__ __launch_bounds__(256) void kan_fused(const float* __restrict__ x,
                                                 const float* __restrict__ C0,
                                                 const float* __restrict__ C1,
                                                 const float* __restrict__ C2,
                                                 float* __restrict__ out) {
    __shared__ float cur[256];
    __shared__ float sw[256][4];
    __shared__ int   st[256];
    const int b = blockIdx.x, tid = threadIdx.x;

    if (tid < 64) stage1(x[(size_t)b * 64 + tid], sw[tid], st[tid]);
    __syncthreads();
    {
        const float a = gather_acc<64, 256>(C0, tid, sw, st);
        __syncthreads();
        cur[tid] = a;
    }
    __syncthreads();

    stage1(cur[tid], sw[tid], st[tid]);
    __syncthreads();
    {
        const float a = gather_acc<256, 256>(C1, tid, sw, st);
        __syncthreads();
        cur[tid] = a;
    }
    __syncthreads();

    stage1(cur[tid], sw[tid], st[tid]);
    __syncthreads();
    if (tid < 64) out[(size_t)b * 64 + tid] = gather_acc<256, 64>(C2, tid, sw, st);
}

// ---------------- launcher --------------------------------------------------

extern "C" void kernel_launch(void* const* d_in, const int* in_sizes, int n_in,
                              void* d_out, int out_size, void* d_ws, size_t ws_size,
                              hipStream_t stream) {
    const float* x  = (const float*)d_in[0];   // (4096, 64)
    const float* C0 = (const float*)d_in[1];   // (64, 256, 64)
    const float* C1 = (const float*)d_in[2];   // (256, 256, 64)
    const float* C2 = (const float*)d_in[3];   // (256, 64, 64)
    float* out = (float*)d_out;                // (4096, 64)

    const size_t WTAB = (size_t)4096 * 256 * 16;   // 16.78 MB
    const size_t KTAB = (size_t)4096 * 256 * 4;    //  4.19 MB
    const size_t CT1  = (size_t)256 * 64 * 256 * 4;// 16.78 MB
    const size_t ACT  = (size_t)4096 * 256 * 4;    //  4.19 MB
    const size_t needA = WTAB + KTAB + CT1 + ACT;  // 41.94 MB == R10-proven
    const size_t needB = WTAB + KTAB + 2 * ACT;    // 29.36 MB (R9 proven)

    if (ws_size >= needA) {
        float4* wA   = (float4*)d_ws;
        int*    kA   = (int*)  ((char*)d_ws + WTAB);
        float*  ct1  = (float*)((char*)d_ws + WTAB + KTAB);   // also parks a1
        float*  actb = (float*)((char*)d_ws + WTAB + KTAB + CT1); // Ct0 then a2
        float*  a1   = ct1;    // 4.19 MB in Ct1 slot, dead before C1 transpose
        float*  ct0  = actb;   // 4.19 MB, dead before a2 written

        transpose_nt<256><<<dim3(2, 8, 64), dim3(32, 8), 0, stream>>>(C0, ct0);
        precomp_x<<<1024, 256, 0, stream>>>(x, wA, kA);
        kan_colgather<64><<<1024, 256, 0, stream>>>(ct0, wA, kA, a1);
        precomp_basis<<<4096, 256, 0, stream>>>(a1, 256, 0, wA, kA, 256 * 4096);
        transpose_nt<256><<<dim3(2, 8, 256), dim3(32, 8), 0, stream>>>(C1, ct1);
        kan_colgather<256><<<1024, 256, 0, stream>>>(ct1, wA, kA, actb /*a2*/);
        precomp_basis<<<4096, 256, 0, stream>>>(actb, 256, 0, wA, kA, 256 * 4096);
        kan_direct<256, 64, 1, false><<<1024, 256, 0, stream>>>(C2, wA, kA, out);
    } else if (ws_size >= needB) {
        float4* wtab = (float4*)d_ws;
        int*    ktab = (int*)((char*)d_ws + WTAB);
        float*  a1T  = (float*)((char*)d_ws + WTAB + KTAB);
        float*  a2T  = a1T + (size_t)4096 * 256;

        precomp_basis<<<1024, 256, 0, stream>>>(x, 64, 0, wtab, ktab, 64 * 4096);
        kan_direct<64, 256, 4, true><<<1024, 256, 0, stream>>>(C0, wtab, ktab, a1T);
        precomp_basis<<<4096, 256, 0, stream>>>(a1T, 256, 1, wtab, ktab, 256 * 4096);
        kan_direct<256, 256, 4, true><<<1024, 256, 0, stream>>>(C1, wtab, ktab, a2T);
        precomp_basis<<<4096, 256, 0, stream>>>(a2T, 256, 1, wtab, ktab, 256 * 4096);
        kan_direct<256, 64, 1, false><<<1024, 256, 0, stream>>>(C2, wtab, ktab, out);
    } else {
        kan_fused<<<NBATCH, 256, 0, stream>>>(x, C0, C1, C2, out);
    }
}